// Round 5
// baseline (340.556 us; speedup 1.0000x reference)
//
#include <hip/hip_runtime.h>
#include <math.h>
#include <stdint.h>

// Problem dims (fixed by setup_inputs)
#define B_N 256
#define C_N 1152
#define I_N 8
#define N_N 10
#define D_N 16

constexpr int C_PER    = 18;             // c's per route block
constexpr int C_CHUNKS = C_N / C_PER;    // 64
constexpr int STAGE_C  = 3;              // c's per W staging round (double-buffered)
constexpr int N_STAGES = 6;
constexpr int BLOCK    = 256;
// route grid = 64 x 16 = 1024 blocks = exactly 4 blocks/CU -> full co-residency.
// Groups of 64 blocks (same btile = blockIdx.y) are data-independent; the only
// cross-block op per routing iteration is a 64-way sum of 2560 floats, done
// with device-scope f32 atomics into a zeroed per-group accumulator sG[pass].

typedef short v8s __attribute__((ext_vector_type(8)));
typedef float v4f __attribute__((ext_vector_type(4)));

// ---- LDS pool (bytes), fused kernel ----
//   wbuf (short): 2 x [3c][10n][16d][8i] = 15360 @ 0      (DMA, linear, dbuf)
//   xs   (short): [18c][16b][8i]         =  4608 @ 15360  (reg-converted once)
//   vst  (float): [16b][164]             = 10496 @ 19968  (accumulated v rows)
//   cfl  (float): [3c][163]              =  1956 @ 30464
constexpr int POOL_BYTES = 32432;   // 31.7 KB -> 4 blocks/CU

// ws layout: sG[3] f32 accumulators, then Wb bf16, then barrier state
constexpr int    SG_FL = 16 * 16 * 164;          // [btile][16b][164] = 41984 fl
constexpr size_t WB_SH = (size_t)C_N * 1280;
constexpr int    BAR_W = 16 * 64;                // 16 groups x 64 uints

#define GLD16(g, l)                                                         \
    __builtin_amdgcn_global_load_lds(                                       \
        (const uint32_t __attribute__((address_space(1)))*)(g),             \
        (uint32_t __attribute__((address_space(3)))*)(l), 16, 0, 0)

// device-scope (LLC) f32 atomic add, no return (sc1 = agent-coherent)
__device__ __forceinline__ void atom_add_sc1(float* p, float v) {
    asm volatile("global_atomic_add_f32 %0, %1, off sc1"
                 :: "v"(p), "v"(v) : "memory");
}

// RNE pack of 2 f32 -> 1 u32 of 2 bf16 (bitwise identical to manual RNE)
__device__ __forceinline__ uint32_t cvtpk(float a, float b) {
    uint32_t r;
    asm("v_cvt_pk_bf16_f32 %0, %1, %2" : "=v"(r) : "v"(a), "v"(b));
    return r;
}
__device__ __forceinline__ float bf2f(short s) {
    return __uint_as_float(((uint32_t)(uint16_t)s) << 16);
}

// ---- K0: W fp32 -> bf16 [c][n][16d*8i]; zero bar + sG accumulators ----
__global__ __launch_bounds__(BLOCK)
void conv_all(const float* __restrict__ W, short* __restrict__ Wb,
              float* __restrict__ sG, uint32_t* __restrict__ bar)
{
    // zeroing happens a dispatch BEFORE any use -> race-free; must run every
    // launch (harness re-poisons ws, and sG must start at 0 for atomics)
    const int gid = blockIdx.x * BLOCK + threadIdx.x;   // < 36864
    if (gid < BAR_W) bar[gid] = 0u;
    for (int i = gid; i < 3 * SG_FL; i += 144 * BLOCK) sG[i] = 0.f;

    const int c0 = blockIdx.x * 8;
    const int cc = threadIdx.x >> 5;        // 8 c's per block
    const int k4 = threadIdx.x & 31;        // 32 float4 per (n,c)
    const float4* W4 = (const float4*)W;
    uint2* dst = (uint2*)Wb;
    for (int n = 0; n < N_N; ++n) {
        float4 v = W4[(size_t)n * 36864 + (size_t)(c0 + cc) * 32 + k4];
        dst[(((size_t)(c0 + cc) * 1280 + n * 128) >> 2) + k4] =
            make_uint2(cvtpk(v.x, v.y), cvtpk(v.z, v.w));
    }
}

// ---- per-group (64-block) fence-free barrier ----
// Each wave drains its own vmem (atomics retire => LLC-visible), block-syncs,
// leader does one relaxed agent fetch_add; last arriver resets + bumps the
// monotonic phase. If !wait, arrive-only (final barrier: non-writers exit).
__device__ __forceinline__ void gbar(uint32_t* bar, int group, uint32_t expect,
                                     bool wait)
{
    asm volatile("s_waitcnt vmcnt(0) lgkmcnt(0)" ::: "memory");
    __syncthreads();
    if (threadIdx.x == 0) {
        uint32_t* cnt = &bar[group * 64];
        uint32_t* ph  = &bar[group * 64 + 32];
        uint32_t a = __hip_atomic_fetch_add(cnt, 1u, __ATOMIC_RELAXED,
                                            __HIP_MEMORY_SCOPE_AGENT);
        if (a == 63u) {
            __hip_atomic_store(cnt, 0u, __ATOMIC_RELAXED,
                               __HIP_MEMORY_SCOPE_AGENT);
            asm volatile("s_waitcnt vmcnt(0)" ::: "memory");
            __hip_atomic_fetch_add(ph, 1u, __ATOMIC_RELAXED,
                                   __HIP_MEMORY_SCOPE_AGENT);
        }
        if (wait) {
            while (__hip_atomic_load(ph, __ATOMIC_RELAXED,
                                     __HIP_MEMORY_SCOPE_AGENT) < expect)
                __builtin_amdgcn_s_sleep(2);
        }
    }
    __syncthreads();
}

// ---- squash s-rows from sG into vst (ACC: accumulate v across passes;
//      l = u.(v0+v1) == b is the routing-logit identity). 160 threads, one
//      (b,n) row each; all 64 blocks redundantly compute identical results. ----
template <bool ACC>
__device__ __forceinline__ void squash_into_vst(const float* __restrict__ sGrp,
                                                float* vst, int tid)
{
    if (tid < 160) {
        const int bb = tid / 10, n = tid - bb * 10;
        const float* rp = sGrp + bb * 164 + n * 16;
        v4f r0, r1, r2, r3;
        asm volatile(
            "global_load_dwordx4 %0, %4, off sc1\n\t"
            "global_load_dwordx4 %1, %5, off sc1\n\t"
            "global_load_dwordx4 %2, %6, off sc1\n\t"
            "global_load_dwordx4 %3, %7, off sc1\n\t"
            "s_waitcnt vmcnt(0)"
            : "=&v"(r0), "=&v"(r1), "=&v"(r2), "=&v"(r3)
            : "v"(rp), "v"(rp + 4), "v"(rp + 8), "v"(rp + 12)
            : "memory");
        float sq = r0[0]*r0[0] + r0[1]*r0[1] + r0[2]*r0[2] + r0[3]*r0[3]
                 + r1[0]*r1[0] + r1[1]*r1[1] + r1[2]*r1[2] + r1[3]*r1[3]
                 + r2[0]*r2[0] + r2[1]*r2[1] + r2[2]*r2[2] + r2[3]*r2[3]
                 + r3[0]*r3[0] + r3[1]*r3[1] + r3[2]*r3[2] + r3[3]*r3[3];
        const float scale = (sq / (1.f + sq)) / (sqrtf(sq) + 1e-8f);
        float* vp = vst + bb * 164 + n * 16;
        if (ACC) {
            *(v4f*)(vp)      += r0 * scale;
            *(v4f*)(vp + 4)  += r1 * scale;
            *(v4f*)(vp + 8)  += r2 * scale;
            *(v4f*)(vp + 12) += r3 * scale;
        } else {
            *(v4f*)(vp)      = r0 * scale;
            *(v4f*)(vp + 4)  = r1 * scale;
            *(v4f*)(vp + 8)  = r2 * scale;
            *(v4f*)(vp + 12) = r3 * scale;
        }
    }
    __syncthreads();
}

// ---- one routing pass; ends with atomic accumulate of sacc into sGout ----
template <bool FIRST>
__device__ __forceinline__ void route_core(
    short* wbuf, const short* xs, const float* vst, float* cfl,
    const short* __restrict__ Wb, float* __restrict__ sGout,
    int chunk, int btile)
{
    const int tid  = threadIdx.x;
    const int wv   = tid >> 6;
    const int lane = tid & 63;
    const int b    = lane & 15;   // D-col / B-col; also A-row m (=d)
    const int quad = lane >> 4;
    const int c0   = chunk * C_PER;

    // ---- prologue: W0/W1 DMA (cached global_load_lds; Wb immutable) ----
    // 480-split: every wave issues exactly 2 GLD16 per stage (uniform vmcnt)
    #pragma unroll
    for (int s0 = 0; s0 < 2; ++s0) {
        const char* src = (const char*)(Wb + (size_t)(c0 + s0 * STAGE_C) * 1280);
        char* dst = (char*)(wbuf + s0 * (STAGE_C * 1280));
        #pragma unroll
        for (int it = 0; it < 2; ++it) {
            int f = tid + BLOCK * it;
            if (f < 480) GLD16(src + f * 16, dst + f * 16);
        }
        asm volatile("" ::: "memory");
    }
    // vmcnt(2): W0 landed; W1 still in flight
    asm volatile("s_waitcnt vmcnt(2) lgkmcnt(0)" ::: "memory");
    __builtin_amdgcn_s_barrier();

    const int ncnt = (wv < 2) ? 3 : 2;   // wave wv owns n = wv, wv+4, (wv+8)
    v4f sacc[3];
    sacc[0] = (v4f){0.f, 0.f, 0.f, 0.f};
    sacc[1] = (v4f){0.f, 0.f, 0.f, 0.f};
    sacc[2] = (v4f){0.f, 0.f, 0.f, 0.f};

    for (int st = 0; st < N_STAGES; ++st) {
        const short* Ws = wbuf + (st & 1) * (STAGE_C * 1280);

        // issue W[st+1] DMA into the buffer last read at stage st-1
        if (st >= 1 && st < N_STAGES - 1) {
            const char* src =
                (const char*)(Wb + (size_t)(c0 + (st + 1) * STAGE_C) * 1280);
            char* dst = (char*)(wbuf + ((st + 1) & 1) * (STAGE_C * 1280));
            #pragma unroll
            for (int it = 0; it < 2; ++it) {
                int f = tid + BLOCK * it;
                if (f < 480) GLD16(src + f * 16, dst + f * 16);
            }
            asm volatile("" ::: "memory");
        }

        if (!FIRST) {
            // ---- sweep1: 30 independent (c,n) chains over 4 waves ----
            #pragma unroll
            for (int k = 0; k < 8; ++k) {
                const int idx = wv + 4 * k;
                if (idx < 30) {
                    const int c = idx / 10;
                    const int n = idx - c * 10;
                    v8s wa = {0, 0, 0, 0, 0, 0, 0, 0};
                    if (quad == 0)
                        wa = *(const v8s*)(Ws + c * 1280 + n * 128 + b * 8);
                    const v8s xb =
                        *(const v8s*)(xs + (st * STAGE_C + c) * 128 + b * 8);
                    v4f u = __builtin_amdgcn_mfma_f32_16x16x32_bf16(
                        wa, xb, (v4f){0.f, 0.f, 0.f, 0.f}, 0, 0, 0);
                    const float4 v4 =
                        *(const float4*)(vst + b * 164 + n * 16 + quad * 4);
                    float l = u[0] * v4.x + u[1] * v4.y + u[2] * v4.z + u[3] * v4.w;
                    l += __shfl_xor(l, 16);
                    l += __shfl_xor(l, 32);
                    const float e1 = __expf(l);   // |l| <~ 3: no max-sub needed
                    if (quad == 0) cfl[c * 163 + n * 16 + b] = e1;
                }
            }
            // publish cfl; W[st+1] DMA stays in flight (no vmcnt drain)
            asm volatile("s_waitcnt lgkmcnt(0)" ::: "memory");
            __builtin_amdgcn_s_barrier();
        }

        // ---- sweep2: K=32 packs 3 c's (quad=c, quad3 zero-padded) ----
        {
            const bool valid = (quad < STAGE_C);
            const int  cl    = valid ? quad : 0;
            const v8s xq =
                *(const v8s*)(xs + (st * STAGE_C + cl) * 128 + b * 8);
            float xf[8];
            #pragma unroll
            for (int j = 0; j < 8; ++j) xf[j] = bf2f(xq[j]);

            if (FIRST) {
                union { v8s s; uint32_t u[4]; } zu;
                zu.u[0] = cvtpk(0.1f * xf[0], 0.1f * xf[1]);
                zu.u[1] = cvtpk(0.1f * xf[2], 0.1f * xf[3]);
                zu.u[2] = cvtpk(0.1f * xf[4], 0.1f * xf[5]);
                zu.u[3] = cvtpk(0.1f * xf[6], 0.1f * xf[7]);
                #pragma unroll
                for (int jj = 0; jj < 3; ++jj) {
                    if (jj < ncnt) {
                        const int n = wv + 4 * jj;
                        v8s wa = {0, 0, 0, 0, 0, 0, 0, 0};
                        if (valid)
                            wa = *(const v8s*)(Ws + cl * 1280 + n * 128 + b * 8);
                        sacc[jj] = __builtin_amdgcn_mfma_f32_16x16x32_bf16(
                            wa, zu.s, sacc[jj], 0, 0, 0);
                    }
                }
            } else {
                float Z = 0.f;
                #pragma unroll
                for (int n = 0; n < N_N; ++n) Z += cfl[cl * 163 + n * 16 + b];
                const float rzv = __builtin_amdgcn_rcpf(Z);
                #pragma unroll
                for (int jj = 0; jj < 3; ++jj) {
                    if (jj < ncnt) {
                        const int n = wv + 4 * jj;
                        const float cv = cfl[cl * 163 + n * 16 + b] * rzv;
                        union { v8s s; uint32_t u[4]; } zu;
                        zu.u[0] = cvtpk(cv * xf[0], cv * xf[1]);
                        zu.u[1] = cvtpk(cv * xf[2], cv * xf[3]);
                        zu.u[2] = cvtpk(cv * xf[4], cv * xf[5]);
                        zu.u[3] = cvtpk(cv * xf[6], cv * xf[7]);
                        v8s wa = {0, 0, 0, 0, 0, 0, 0, 0};
                        if (valid)
                            wa = *(const v8s*)(Ws + cl * 1280 + n * 128 + b * 8);
                        sacc[jj] = __builtin_amdgcn_mfma_f32_16x16x32_bf16(
                            wa, zu.s, sacc[jj], 0, 0, 0);
                    }
                }
            }
        }

        // end of stage: W[st+1] had a full stage of compute to land
        asm volatile("s_waitcnt vmcnt(0) lgkmcnt(0)" ::: "memory");
        __builtin_amdgcn_s_barrier();
    }

    // ---- accumulate partial s straight from registers into the group's
    //      device accumulator (order-independent f32 sum, 12 atomics/thread).
    //      Retired before the following gbar's vmcnt(0) drain. ----
    float* sgb = sGout + (size_t)btile * 2624;
    #pragma unroll
    for (int jj = 0; jj < 3; ++jj) {
        if (jj < ncnt) {
            const int n = wv + 4 * jj;
            float* p = sgb + b * 164 + n * 16 + quad * 4;
            #pragma unroll
            for (int r = 0; r < 4; ++r)
                atom_add_sc1(p + r, sacc[jj][r]);
        }
    }
}

// ---- whole routing pipeline, ONE dispatch, 3 group barriers total ----
__global__ __launch_bounds__(BLOCK, 4)
void fused_route(const float* __restrict__ x, const short* __restrict__ Wb,
                 float* __restrict__ sG, float* __restrict__ out,
                 uint32_t* bar)
{
    __shared__ __align__(16) char pool[POOL_BYTES];
    short* wbuf = (short*)pool;
    short* xs   = (short*)(pool + 15360);
    float* vst  = (float*)(pool + 19968);
    float* cfl  = (float*)(pool + 30464);

    const int chunk = blockIdx.x;
    const int btile = blockIdx.y;     // == group id
    const int tid   = threadIdx.x;
    const int gb0   = btile * 16;
    const int c0    = chunk * C_PER;

    float* sG0 = sG;
    float* sG1 = sG + SG_FL;
    float* sG2 = sG + 2 * SG_FL;

    // ---- xs: convert x fp32 -> bf16 straight into LDS; persists all passes ----
    {
        const float4* x4 = (const float4*)x;
        #pragma unroll
        for (int it = 0; it < 3; ++it) {
            int f = tid + BLOCK * it;
            if (f < 576) {
                int b = f / 36, r = f - b * 36;  // r: 36 float4 per b (18c*8i)
                float4 v = x4[(size_t)(gb0 + b) * 2304 + c0 * 2 + r];
                int cp = r >> 1, i0 = (r & 1) * 4;
                *(uint2*)(xs + cp * 128 + b * 8 + i0) =
                    make_uint2(cvtpk(v.x, v.y), cvtpk(v.z, v.w));
            }
        }
        asm volatile("s_waitcnt vmcnt(0)" ::: "memory");
    }

    // pass 0: c = 0.1 uniform; accumulate s0
    route_core<true>(wbuf, xs, vst, cfl, Wb, sG0, chunk, btile);
    gbar(bar, btile, 1, true);

    // pass 1: v = squash(s0); accumulate s1
    squash_into_vst<false>(sG0 + (size_t)btile * 2624, vst, tid);
    route_core<false>(wbuf, xs, vst, cfl, Wb, sG1, chunk, btile);
    gbar(bar, btile, 2, true);

    // pass 2: v += squash(s1)  (l = u.(v0+v1) == accumulated logit b);
    // accumulate s2
    squash_into_vst<true>(sG1 + (size_t)btile * 2624, vst, tid);
    route_core<false>(wbuf, xs, vst, cfl, Wb, sG2, chunk, btile);

    // final: all arrive; only writer blocks (chunk < 40) wait + emit output
    const bool writer = (chunk < 40);
    gbar(bar, btile, 3, writer);
    if (writer && tid < 64) {
        const int k  = chunk * 4 + (tid >> 4);        // 0..159 (b,n) rows
        const int bb = k / 10, n = k - bb * 10, d = tid & 15;
        const float* sp = sG2 + (size_t)btile * 2624 + bb * 164 + n * 16 + d;
        float sv;
        asm volatile("global_load_dword %0, %1, off sc1\n\t"
                     "s_waitcnt vmcnt(0)"
                     : "=&v"(sv) : "v"(sp) : "memory");
        float sq = sv * sv;
        sq += __shfl_xor(sq, 1);
        sq += __shfl_xor(sq, 2);
        sq += __shfl_xor(sq, 4);
        sq += __shfl_xor(sq, 8);
        const float scale = (sq / (1.f + sq)) / (sqrtf(sq) + 1e-8f);
        out[((size_t)(gb0 + bb) * 10 + n) * 16 + d] = scale * sv;
    }
}

extern "C" void kernel_launch(void* const* d_in, const int* in_sizes, int n_in,
                              void* d_out, int out_size, void* d_ws, size_t ws_size,
                              hipStream_t stream)
{
    const float* x = (const float*)d_in[0];
    const float* W = (const float*)d_in[1];
    float* out  = (float*)d_out;

    float* sG = (float*)d_ws;                     // 3 x SG_FL floats
    short* Wb = (short*)(sG + 3 * SG_FL);
    uint32_t* bar = (uint32_t*)(Wb + WB_SH);

    conv_all<<<dim3(144), BLOCK, 0, stream>>>(W, Wb, sG, bar);
    fused_route<<<dim3(C_CHUNKS, 16), BLOCK, 0, stream>>>(x, Wb, sG, out, bar);
}

// Round 6
// 121.575 us; speedup vs baseline: 2.8012x; 2.8012x over previous
//
#include <hip/hip_runtime.h>
#include <math.h>
#include <stdint.h>

// Problem dims (fixed by setup_inputs)
#define B_N 256
#define C_N 1152
#define I_N 8
#define N_N 10
#define D_N 16

constexpr int C_PER    = 18;             // c's per route block
constexpr int C_CHUNKS = C_N / C_PER;    // 64
constexpr int STAGE_C  = 3;              // c's per W staging round (double-buffered)
constexpr int N_STAGES = 6;
constexpr int BLOCK    = 256;
// route grid = 64 x 16 = 1024 blocks = exactly 4 blocks/CU -> full co-residency.
// Groups of 64 blocks (same btile = blockIdx.y) are data-independent; all
// barriers are per-group (64 arrivals). NO atomics (R5 lesson: f32 atomics
// write-through 16B/op serialized -> 4.4x regression).

typedef short v8s __attribute__((ext_vector_type(8)));
typedef float v4f __attribute__((ext_vector_type(4)));

// ---- LDS pool (bytes), fused kernel ----
//   wbuf (short): 2 x [3c][10n][16d][8i] = 15360 @ 0      (DMA, linear, dbuf)
//   xs   (short): [18c][16b][8i]         =  4608 @ 15360  (reg-converted once)
//   vst  (float): [16b][164]             = 10496 @ 19968  (sc1 reg-staged)
//   cfl  (float): [3c][163]              =  1956 @ 30464
constexpr int POOL_BYTES = 32432;   // 31.7 KB -> 4 blocks/CU

// ws layout (floats unless noted):
constexpr size_t VSTG_FL = 16 * 16 * 164;
constexpr size_t PS_FL   = (size_t)C_CHUNKS * B_N * 160;
constexpr size_t WB_SH   = (size_t)C_N * 1280;
constexpr int    BAR_W   = 16 * 64;  // 16 groups x 64 uints (256B stride)

#define GLD16(g, l)                                                         \
    __builtin_amdgcn_global_load_lds(                                       \
        (const uint32_t __attribute__((address_space(1)))*)(g),             \
        (uint32_t __attribute__((address_space(3)))*)(l), 16, 0, 0)

// ---- agent-coherent (LLC, bypass per-XCD L2) 16B load/store: sc1 flag ----
__device__ __forceinline__ void st16_sc1(float* p, v4f v) {
    asm volatile("global_store_dwordx4 %0, %1, off sc1"
                 :: "v"(p), "v"(v) : "memory");
}
__device__ __forceinline__ v4f ld16_sc1(const float* p) {
    v4f v;
    asm volatile("global_load_dwordx4 %0, %1, off sc1\n\t"
                 "s_waitcnt vmcnt(0)"
                 : "=&v"(v) : "v"(p) : "memory");
    return v;
}

// RNE pack of 2 f32 -> 1 u32 of 2 bf16 (bitwise identical to manual RNE)
__device__ __forceinline__ uint32_t cvtpk(float a, float b) {
    uint32_t r;
    asm("v_cvt_pk_bf16_f32 %0, %1, %2" : "=v"(r) : "v"(a), "v"(b));
    return r;
}
__device__ __forceinline__ float bf2f(short s) {
    return __uint_as_float(((uint32_t)(uint16_t)s) << 16);
}

// ---- K0: W fp32 -> bf16 [c][n][16d*8i] + barrier-state init ----
__global__ __launch_bounds__(BLOCK)
void conv_all(const float* __restrict__ W, short* __restrict__ Wb,
              uint32_t* __restrict__ bar)
{
    // barrier counters zeroed here, a dispatch BEFORE any use -> race-free
    // (harness re-poisons ws between iterations, so this must run every call)
    if (blockIdx.x == 0) {
        for (int i = threadIdx.x; i < BAR_W; i += BLOCK) bar[i] = 0u;
    }
    const int c0 = blockIdx.x * 8;
    const int cc = threadIdx.x >> 5;        // 8 c's per block
    const int k4 = threadIdx.x & 31;        // 32 float4 per (n,c)
    const float4* W4 = (const float4*)W;
    uint2* dst = (uint2*)Wb;
    for (int n = 0; n < N_N; ++n) {
        float4 v = W4[(size_t)n * 36864 + (size_t)(c0 + cc) * 32 + k4];
        dst[(((size_t)(c0 + cc) * 1280 + n * 128) >> 2) + k4] =
            make_uint2(cvtpk(v.x, v.y), cvtpk(v.z, v.w));
    }
}

// ---- per-group (64-block) fence-free barrier ----
// Entry vmcnt(0) drains this block's sc1 stores AND any in-flight W prefetch
// DMA (so prestaged passes need no prologue wait). Leader: one relaxed agent
// fetch_add; last arriver resets + bumps the monotonic phase; spin on phase.
__device__ __forceinline__ void gbar(uint32_t* bar, int group, uint32_t expect)
{
    asm volatile("s_waitcnt vmcnt(0) lgkmcnt(0)" ::: "memory");
    __syncthreads();
    if (threadIdx.x == 0) {
        uint32_t* cnt = &bar[group * 64];
        uint32_t* ph  = &bar[group * 64 + 32];
        uint32_t a = __hip_atomic_fetch_add(cnt, 1u, __ATOMIC_RELAXED,
                                            __HIP_MEMORY_SCOPE_AGENT);
        if (a == 63u) {
            __hip_atomic_store(cnt, 0u, __ATOMIC_RELAXED,
                               __HIP_MEMORY_SCOPE_AGENT);
            asm volatile("s_waitcnt vmcnt(0)" ::: "memory");
            __hip_atomic_fetch_add(ph, 1u, __ATOMIC_RELAXED,
                                   __HIP_MEMORY_SCOPE_AGENT);
        }
        while (__hip_atomic_load(ph, __ATOMIC_RELAXED,
                                 __HIP_MEMORY_SCOPE_AGENT) < expect)
            __builtin_amdgcn_s_sleep(2);
    }
    __syncthreads();
}

// ---- one routing pass ----
// PRESTAGE: W stages 0/1 already in wbuf (prefetched at previous pass tail,
//           drained by the interleaving gbar) -> skip prologue staging+wait.
// PREFETCH: at tail (after the last stage-end barrier frees wbuf), re-issue
//           stage-0/1 W DMA for the NEXT pass (same c-slice); left in flight.
template <bool FIRST, bool PRESTAGE, bool PREFETCH>
__device__ __forceinline__ void route_core(
    short* wbuf, const short* xs, const float* vst_c, float* vst, float* cfl,
    const short* __restrict__ Wb, const float* __restrict__ vstG,
    float* __restrict__ p_s, int chunk, int btile)
{
    const int tid  = threadIdx.x;
    const int wv   = tid >> 6;
    const int lane = tid & 63;
    const int b    = lane & 15;   // D-col / B-col; also A-row m (=d)
    const int quad = lane >> 4;
    const int gb0  = btile * 16;
    const int c0   = chunk * C_PER;

    // ---- prologue ----
    if (!PRESTAGE) {
        // W0 then W1 via cached global_load_lds (Wb immutable -> L2-warm);
        // 480-split: every wave issues exactly 2 GLD16 per stage
        #pragma unroll
        for (int s0 = 0; s0 < 2; ++s0) {
            const char* src =
                (const char*)(Wb + (size_t)(c0 + s0 * STAGE_C) * 1280);
            char* dst = (char*)(wbuf + s0 * (STAGE_C * 1280));
            #pragma unroll
            for (int it = 0; it < 2; ++it) {
                int f = tid + BLOCK * it;
                if (f < 480) GLD16(src + f * 16, dst + f * 16);
            }
            asm volatile("" ::: "memory");
        }
        // vmcnt(2): W0 landed; W1 still in flight into stage 0
        asm volatile("s_waitcnt vmcnt(2) lgkmcnt(0)" ::: "memory");
        __builtin_amdgcn_s_barrier();
    }
    if (!FIRST) {
        // vst via sc1 reg-staging (cross-block data -> LLC-coherent loads)
        const float* src = vstG + (size_t)btile * 2624;
        const int f0 = tid;                       // < 656 always
        const int f1 = tid + 256;                 // < 656 always
        int f2 = tid + 512; f2 = (f2 < 656) ? f2 : 655;  // clamp: uniform count
        v4f t0, t1, t2;
        asm volatile(
            "global_load_dwordx4 %0, %3, off sc1\n\t"
            "global_load_dwordx4 %1, %4, off sc1\n\t"
            "global_load_dwordx4 %2, %5, off sc1\n\t"
            "s_waitcnt vmcnt(0)"
            : "=&v"(t0), "=&v"(t1), "=&v"(t2)
            : "v"(src + f0 * 4), "v"(src + f1 * 4), "v"(src + f2 * 4)
            : "memory");
        *(v4f*)((char*)vst + f0 * 16) = t0;
        *(v4f*)((char*)vst + f1 * 16) = t1;
        *(v4f*)((char*)vst + f2 * 16) = t2;   // f2 clamp: benign dup write
        asm volatile("s_waitcnt lgkmcnt(0)" ::: "memory");
        __builtin_amdgcn_s_barrier();
    }

    const int ncnt = (wv < 2) ? 3 : 2;   // wave wv owns n = wv, wv+4, (wv+8)
    v4f sacc[3];
    sacc[0] = (v4f){0.f, 0.f, 0.f, 0.f};
    sacc[1] = (v4f){0.f, 0.f, 0.f, 0.f};
    sacc[2] = (v4f){0.f, 0.f, 0.f, 0.f};

    for (int st = 0; st < N_STAGES; ++st) {
        const short* Ws = wbuf + (st & 1) * (STAGE_C * 1280);

        // issue W[st+1] DMA into the buffer last read at stage st-1
        if (st >= 1 && st < N_STAGES - 1) {
            const char* src =
                (const char*)(Wb + (size_t)(c0 + (st + 1) * STAGE_C) * 1280);
            char* dst = (char*)(wbuf + ((st + 1) & 1) * (STAGE_C * 1280));
            #pragma unroll
            for (int it = 0; it < 2; ++it) {
                int f = tid + BLOCK * it;
                if (f < 480) GLD16(src + f * 16, dst + f * 16);
            }
            asm volatile("" ::: "memory");
        }

        if (!FIRST) {
            // ---- sweep1: 30 independent (c,n) chains over 4 waves ----
            #pragma unroll
            for (int k = 0; k < 8; ++k) {
                const int idx = wv + 4 * k;
                if (idx < 30) {
                    const int c = idx / 10;
                    const int n = idx - c * 10;
                    v8s wa = {0, 0, 0, 0, 0, 0, 0, 0};
                    if (quad == 0)
                        wa = *(const v8s*)(Ws + c * 1280 + n * 128 + b * 8);
                    const v8s xb =
                        *(const v8s*)(xs + (st * STAGE_C + c) * 128 + b * 8);
                    v4f u = __builtin_amdgcn_mfma_f32_16x16x32_bf16(
                        wa, xb, (v4f){0.f, 0.f, 0.f, 0.f}, 0, 0, 0);
                    const float4 v4 =
                        *(const float4*)(vst_c + b * 164 + n * 16 + quad * 4);
                    float l = u[0] * v4.x + u[1] * v4.y + u[2] * v4.z + u[3] * v4.w;
                    l += __shfl_xor(l, 16);
                    l += __shfl_xor(l, 32);
                    const float e1 = __expf(l);   // |l| <~ 3: no max-sub needed
                    if (quad == 0) cfl[c * 163 + n * 16 + b] = e1;
                }
            }
            // publish cfl; W[st+1] DMA stays in flight (no vmcnt drain)
            asm volatile("s_waitcnt lgkmcnt(0)" ::: "memory");
            __builtin_amdgcn_s_barrier();
        }

        // ---- sweep2: K=32 packs 3 c's (quad=c, quad3 zero-padded) ----
        {
            const bool valid = (quad < STAGE_C);
            const int  cl    = valid ? quad : 0;
            const v8s xq =
                *(const v8s*)(xs + (st * STAGE_C + cl) * 128 + b * 8);
            float xf[8];
            #pragma unroll
            for (int j = 0; j < 8; ++j) xf[j] = bf2f(xq[j]);

            if (FIRST) {
                union { v8s s; uint32_t u[4]; } zu;
                zu.u[0] = cvtpk(0.1f * xf[0], 0.1f * xf[1]);
                zu.u[1] = cvtpk(0.1f * xf[2], 0.1f * xf[3]);
                zu.u[2] = cvtpk(0.1f * xf[4], 0.1f * xf[5]);
                zu.u[3] = cvtpk(0.1f * xf[6], 0.1f * xf[7]);
                #pragma unroll
                for (int jj = 0; jj < 3; ++jj) {
                    if (jj < ncnt) {
                        const int n = wv + 4 * jj;
                        v8s wa = {0, 0, 0, 0, 0, 0, 0, 0};
                        if (valid)
                            wa = *(const v8s*)(Ws + cl * 1280 + n * 128 + b * 8);
                        sacc[jj] = __builtin_amdgcn_mfma_f32_16x16x32_bf16(
                            wa, zu.s, sacc[jj], 0, 0, 0);
                    }
                }
            } else {
                float Z = 0.f;
                #pragma unroll
                for (int n = 0; n < N_N; ++n) Z += cfl[cl * 163 + n * 16 + b];
                const float rzv = __builtin_amdgcn_rcpf(Z);
                #pragma unroll
                for (int jj = 0; jj < 3; ++jj) {
                    if (jj < ncnt) {
                        const int n = wv + 4 * jj;
                        const float cv = cfl[cl * 163 + n * 16 + b] * rzv;
                        union { v8s s; uint32_t u[4]; } zu;
                        zu.u[0] = cvtpk(cv * xf[0], cv * xf[1]);
                        zu.u[1] = cvtpk(cv * xf[2], cv * xf[3]);
                        zu.u[2] = cvtpk(cv * xf[4], cv * xf[5]);
                        zu.u[3] = cvtpk(cv * xf[6], cv * xf[7]);
                        v8s wa = {0, 0, 0, 0, 0, 0, 0, 0};
                        if (valid)
                            wa = *(const v8s*)(Ws + cl * 1280 + n * 128 + b * 8);
                        sacc[jj] = __builtin_amdgcn_mfma_f32_16x16x32_bf16(
                            wa, zu.s, sacc[jj], 0, 0, 0);
                    }
                }
            }
        }

        // end of stage: W[st+1] had a full stage of compute to land
        asm volatile("s_waitcnt vmcnt(0) lgkmcnt(0)" ::: "memory");
        __builtin_amdgcn_s_barrier();
    }

    // ---- tail: prefetch next pass's W (same c-slice) into freed wbuf;
    //      drains for free inside the following gbar's vmcnt(0) ----
    if (PREFETCH) {
        #pragma unroll
        for (int s0 = 0; s0 < 2; ++s0) {
            const char* src =
                (const char*)(Wb + (size_t)(c0 + s0 * STAGE_C) * 1280);
            char* dst = (char*)(wbuf + s0 * (STAGE_C * 1280));
            #pragma unroll
            for (int it = 0; it < 2; ++it) {
                int f = tid + BLOCK * it;
                if (f < 480) GLD16(src + f * 16, dst + f * 16);
            }
            asm volatile("" ::: "memory");
        }
    }

    // ---- direct reg -> p_s sc1 stores (no comb LDS round-trip) ----
    #pragma unroll
    for (int jj = 0; jj < 3; ++jj) {
        if (jj < ncnt) {
            const int n = wv + 4 * jj;
            st16_sc1(&p_s[((size_t)chunk * B_N + gb0 + b) * 160 + n * 16 + quad * 4],
                     sacc[jj]);
        }
    }
}

// ---- reduce+squash, group-local: 160 g's over the group's 64 blocks ----
__device__ __forceinline__ void reduce_core(const float* __restrict__ p_s,
                                            float* __restrict__ vstG,
                                            float* __restrict__ out,
                                            int phase, int chunk, int btile)
{
    const int wv   = threadIdx.x >> 6;
    const int lane = threadIdx.x & 63;
    const int k    = wv * 64 + chunk;        // 0..191; valid < 160
    if (k >= 160) return;                    // wave-uniform (chunk is uniform)
    const int bb = k / 10, n = k - bb * 10;  // bb in [0,16), n in [0,10)
    const int g  = (btile * 16 + bb) * 10 + n;
    const int q = lane & 3;
    const int h = lane >> 2;

    // p_s written cross-block -> sc1 loads (bypass possibly-stale L2)
    const float* base = p_s + (size_t)g * D_N + q * 4;
    v4f a0, a1, a2, a3;
    asm volatile(
        "global_load_dwordx4 %0, %4, off sc1\n\t"
        "global_load_dwordx4 %1, %5, off sc1\n\t"
        "global_load_dwordx4 %2, %6, off sc1\n\t"
        "global_load_dwordx4 %3, %7, off sc1\n\t"
        "s_waitcnt vmcnt(0)"
        : "=&v"(a0), "=&v"(a1), "=&v"(a2), "=&v"(a3)
        : "v"(base + (size_t)(h)      * 40960),
          "v"(base + (size_t)(h + 16) * 40960),
          "v"(base + (size_t)(h + 32) * 40960),
          "v"(base + (size_t)(h + 48) * 40960)
        : "memory");
    v4f s = a0 + a1 + a2 + a3;

    #pragma unroll
    for (int off = 4; off < 64; off <<= 1) {
        s[0] += __shfl_xor(s[0], off);
        s[1] += __shfl_xor(s[1], off);
        s[2] += __shfl_xor(s[2], off);
        s[3] += __shfl_xor(s[3], off);
    }
    float sq = s[0] * s[0] + s[1] * s[1] + s[2] * s[2] + s[3] * s[3];
    sq += __shfl_xor(sq, 1);
    sq += __shfl_xor(sq, 2);

    const float scale = (sq / (1.f + sq)) / (sqrtf(sq) + 1e-8f);
    const v4f v = {scale * s[0], scale * s[1], scale * s[2], scale * s[3]};

    if (h == 0) {
        if (phase == 2) {
            *(float4*)(&out[(size_t)g * D_N + q * 4]) =
                make_float4(v[0], v[1], v[2], v[3]);   // plain: kernel-end flush
        } else {
            float* vp = vstG + (size_t)btile * 2624 + bb * 164 + n * 16 + q * 4;
            if (phase == 0) {
                st16_sc1(vp, v);
            } else {
                v4f o = ld16_sc1(vp);   // own phase-0 sc1 store, via LLC
                st16_sc1(vp, o + v);
            }
        }
    }
}

// ---- whole routing pipeline, ONE dispatch, per-group barriers only ----
__global__ __launch_bounds__(BLOCK, 4)
void fused_route(const float* __restrict__ x, const short* __restrict__ Wb,
                 float* __restrict__ vstG, float* __restrict__ p_s,
                 float* __restrict__ out, uint32_t* bar)
{
    __shared__ __align__(16) char pool[POOL_BYTES];
    short* wbuf = (short*)pool;
    short* xs   = (short*)(pool + 15360);
    float* vst  = (float*)(pool + 19968);
    float* cfl  = (float*)(pool + 30464);

    const int chunk = blockIdx.x;
    const int btile = blockIdx.y;     // == group id
    const int tid   = threadIdx.x;
    const int gb0   = btile * 16;
    const int c0    = chunk * C_PER;

    // ---- xs: convert x fp32 -> bf16 straight into LDS; persists all passes ----
    {
        const float4* x4 = (const float4*)x;
        #pragma unroll
        for (int it = 0; it < 3; ++it) {
            int f = tid + BLOCK * it;
            if (f < 576) {
                int b = f / 36, r = f - b * 36;  // r: 36 float4 per b (18c*8i)
                float4 v = x4[(size_t)(gb0 + b) * 2304 + c0 * 2 + r];
                int cp = r >> 1, i0 = (r & 1) * 4;
                *(uint2*)(xs + cp * 128 + b * 8 + i0) =
                    make_uint2(cvtpk(v.x, v.y), cvtpk(v.z, v.w));
            }
        }
        // drain x loads so the prologue's vmcnt(2) counts only W DMA
        asm volatile("s_waitcnt vmcnt(0)" ::: "memory");
    }

    // pass 0: c = 0.1 uniform; W staged in prologue; prefetch W at tail
    route_core<true, false, true>(wbuf, xs, vst, vst, cfl, Wb, vstG, p_s,
                                  chunk, btile);
    gbar(bar, btile, 1);
    reduce_core(p_s, vstG, out, 0, chunk, btile);
    gbar(bar, btile, 2);

    // pass 1: W prestaged (drained at gbar 1); prefetch again at tail
    route_core<false, true, true>(wbuf, xs, vst, vst, cfl, Wb, vstG, p_s,
                                  chunk, btile);
    gbar(bar, btile, 3);
    reduce_core(p_s, vstG, out, 1, chunk, btile);
    gbar(bar, btile, 4);

    // pass 2: W prestaged; no prefetch
    route_core<false, true, false>(wbuf, xs, vst, vst, cfl, Wb, vstG, p_s,
                                   chunk, btile);
    gbar(bar, btile, 5);
    reduce_core(p_s, vstG, out, 2, chunk, btile);
}

extern "C" void kernel_launch(void* const* d_in, const int* in_sizes, int n_in,
                              void* d_out, int out_size, void* d_ws, size_t ws_size,
                              hipStream_t stream)
{
    const float* x = (const float*)d_in[0];
    const float* W = (const float*)d_in[1];
    float* out  = (float*)d_out;

    float* vstG = (float*)d_ws;
    float* p_s  = vstG + VSTG_FL;
    short* Wb   = (short*)(p_s + PS_FL);
    uint32_t* bar = (uint32_t*)(Wb + WB_SH);

    conv_all<<<dim3(144), BLOCK, 0, stream>>>(W, Wb, bar);
    fused_route<<<dim3(C_CHUNKS, 16), BLOCK, 0, stream>>>(x, Wb, vstG, p_s, out, bar);
}

// Round 7
// 119.043 us; speedup vs baseline: 2.8608x; 1.0213x over previous
//
#include <hip/hip_runtime.h>
#include <math.h>
#include <stdint.h>

// Problem dims (fixed by setup_inputs)
#define B_N 256
#define C_N 1152
#define I_N 8
#define N_N 10
#define D_N 16

constexpr int C_PER    = 18;             // c's per route block
constexpr int C_CHUNKS = C_N / C_PER;    // 64
constexpr int STAGE_C  = 3;              // c's per W staging round (double-buffered)
constexpr int N_STAGES = 6;
constexpr int BLOCK    = 256;
// route grid = 64 x 16 = 1024 blocks = exactly 4 blocks/CU -> full co-residency.
// Groups of 64 blocks (same btile = blockIdx.y) are data-independent; all
// barriers are per-group (64 arrivals). NO atomics (R5 lesson).

typedef short v8s __attribute__((ext_vector_type(8)));
typedef float v4f __attribute__((ext_vector_type(4)));

// ---- LDS pool (bytes), fused kernel ----
//   wbuf (short): 2 x [3c][10n][16d][8i] = 15360 @ 0      (DMA, linear, dbuf)
//   xs   (short): [18c][16b][8i]         =  4608 @ 15360  (reg-converted once)
//   cfl  (float): [3c][163]              =  1956 @ 19968
//   (vst REMOVED: v rows live in 5 VGPR quads per lane -> no LDS reads,
//    no staging phase/barrier, no stride-164 bank conflicts)
constexpr int POOL_BYTES = 21952;   // 21.4 KB

// ws layout (floats unless noted):
constexpr size_t VSTG_FL = 16 * 16 * 164;
constexpr size_t PS_FL   = (size_t)C_CHUNKS * B_N * 160;
constexpr size_t WB_SH   = (size_t)C_N * 1280;
constexpr int    BAR_W   = 16 * 64;  // 16 groups x 64 uints (256B stride)

#define GLD16(g, l)                                                         \
    __builtin_amdgcn_global_load_lds(                                       \
        (const uint32_t __attribute__((address_space(1)))*)(g),             \
        (uint32_t __attribute__((address_space(3)))*)(l), 16, 0, 0)

// ---- agent-coherent (LLC, bypass per-XCD L2) 16B load/store: sc1 flag ----
__device__ __forceinline__ void st16_sc1(float* p, v4f v) {
    asm volatile("global_store_dwordx4 %0, %1, off sc1"
                 :: "v"(p), "v"(v) : "memory");
}
__device__ __forceinline__ v4f ld16_sc1(const float* p) {
    v4f v;
    asm volatile("global_load_dwordx4 %0, %1, off sc1\n\t"
                 "s_waitcnt vmcnt(0)"
                 : "=&v"(v) : "v"(p) : "memory");
    return v;
}

// RNE pack of 2 f32 -> 1 u32 of 2 bf16 (bitwise identical to manual RNE)
__device__ __forceinline__ uint32_t cvtpk(float a, float b) {
    uint32_t r;
    asm("v_cvt_pk_bf16_f32 %0, %1, %2" : "=v"(r) : "v"(a), "v"(b));
    return r;
}
__device__ __forceinline__ float bf2f(short s) {
    return __uint_as_float(((uint32_t)(uint16_t)s) << 16);
}

// ---- K0: W fp32 -> bf16 [c][n][16d*8i] + barrier-state init ----
__global__ __launch_bounds__(BLOCK)
void conv_all(const float* __restrict__ W, short* __restrict__ Wb,
              uint32_t* __restrict__ bar)
{
    // barrier counters zeroed here, a dispatch BEFORE any use -> race-free
    if (blockIdx.x == 0) {
        for (int i = threadIdx.x; i < BAR_W; i += BLOCK) bar[i] = 0u;
    }
    const int c0 = blockIdx.x * 8;
    const int cc = threadIdx.x >> 5;        // 8 c's per block
    const int k4 = threadIdx.x & 31;        // 32 float4 per (n,c)
    const float4* W4 = (const float4*)W;
    uint2* dst = (uint2*)Wb;
    for (int n = 0; n < N_N; ++n) {
        float4 v = W4[(size_t)n * 36864 + (size_t)(c0 + cc) * 32 + k4];
        dst[(((size_t)(c0 + cc) * 1280 + n * 128) >> 2) + k4] =
            make_uint2(cvtpk(v.x, v.y), cvtpk(v.z, v.w));
    }
}

// ---- per-group (64-block) fence-free barrier ----
__device__ __forceinline__ void gbar(uint32_t* bar, int group, uint32_t expect)
{
    asm volatile("s_waitcnt vmcnt(0) lgkmcnt(0)" ::: "memory");
    __syncthreads();
    if (threadIdx.x == 0) {
        uint32_t* cnt = &bar[group * 64];
        uint32_t* ph  = &bar[group * 64 + 32];
        uint32_t a = __hip_atomic_fetch_add(cnt, 1u, __ATOMIC_RELAXED,
                                            __HIP_MEMORY_SCOPE_AGENT);
        if (a == 63u) {
            __hip_atomic_store(cnt, 0u, __ATOMIC_RELAXED,
                               __HIP_MEMORY_SCOPE_AGENT);
            asm volatile("s_waitcnt vmcnt(0)" ::: "memory");
            __hip_atomic_fetch_add(ph, 1u, __ATOMIC_RELAXED,
                                   __HIP_MEMORY_SCOPE_AGENT);
        }
        while (__hip_atomic_load(ph, __ATOMIC_RELAXED,
                                 __HIP_MEMORY_SCOPE_AGENT) < expect)
            __builtin_amdgcn_s_sleep(2);
    }
    __syncthreads();
}

// ---- one routing pass ----
// v rows in REGISTERS: wave wv's sweep1 chains (idx = wv+4k) touch exactly 5
// distinct n's, and chain k always uses vreg[k%5] where vreg[j] holds
// n=(wv+4j)%10 (verified identity: 4k == 4(k%5) mod 10). Register index is
// compile-time -> no scratch (rule #20), no LDS vst, no staging barrier.
template <bool FIRST, bool PRESTAGE, bool PREFETCH>
__device__ __forceinline__ void route_core(
    short* wbuf, const short* xs, float* cfl,
    const short* __restrict__ Wb, const float* __restrict__ vstG,
    float* __restrict__ p_s, int chunk, int btile)
{
    const int tid  = threadIdx.x;
    const int wv   = tid >> 6;
    const int lane = tid & 63;
    const int b    = lane & 15;   // D-col / B-col; also A-row m (=d)
    const int quad = lane >> 4;
    const int gb0  = btile * 16;
    const int c0   = chunk * C_PER;

    // ---- prologue ----
    if (!PRESTAGE) {
        // W0 then W1 via cached global_load_lds (Wb immutable -> L2-warm);
        // 480-split: every wave issues exactly 2 GLD16 per stage
        #pragma unroll
        for (int s0 = 0; s0 < 2; ++s0) {
            const char* src =
                (const char*)(Wb + (size_t)(c0 + s0 * STAGE_C) * 1280);
            char* dst = (char*)(wbuf + s0 * (STAGE_C * 1280));
            #pragma unroll
            for (int it = 0; it < 2; ++it) {
                int f = tid + BLOCK * it;
                if (f < 480) GLD16(src + f * 16, dst + f * 16);
            }
            asm volatile("" ::: "memory");
        }
        // vmcnt(2): W0 landed; W1 still in flight into stage 0
        asm volatile("s_waitcnt vmcnt(2) lgkmcnt(0)" ::: "memory");
        __builtin_amdgcn_s_barrier();
    }

    v4f vr0 = {0.f,0.f,0.f,0.f}, vr1 = vr0, vr2 = vr0, vr3 = vr0, vr4 = vr0;
    if (!FIRST) {
        // 5 sc1 v-row loads straight to regs (vstG written cross-block; LLC).
        // vreg[j] <- vstG[btile][b][n_j*16 + quad*4], n_j = (wv+4j)%10.
        const float* base = vstG + (size_t)btile * 2624 + b * 164 + quad * 4;
        const int n2 = (wv + 8) % 10;
        const float* a0 = base + wv * 16;
        const float* a1 = base + (wv + 4) * 16;
        const float* a2 = base + n2 * 16;
        const float* a3 = base + (wv + 2) * 16;
        const float* a4 = base + (wv + 6) * 16;
        asm volatile(
            "global_load_dwordx4 %0, %5, off sc1\n\t"
            "global_load_dwordx4 %1, %6, off sc1\n\t"
            "global_load_dwordx4 %2, %7, off sc1\n\t"
            "global_load_dwordx4 %3, %8, off sc1\n\t"
            "global_load_dwordx4 %4, %9, off sc1\n\t"
            "s_waitcnt vmcnt(0)"
            : "=&v"(vr0), "=&v"(vr1), "=&v"(vr2), "=&v"(vr3), "=&v"(vr4)
            : "v"(a0), "v"(a1), "v"(a2), "v"(a3), "v"(a4)
            : "memory");
        // no barrier needed: regs are private; Ws prestage was drained at gbar
    }

    const int ncnt = (wv < 2) ? 3 : 2;   // wave wv owns n = wv, wv+4, (wv+8)
    v4f sacc[3];
    sacc[0] = (v4f){0.f, 0.f, 0.f, 0.f};
    sacc[1] = (v4f){0.f, 0.f, 0.f, 0.f};
    sacc[2] = (v4f){0.f, 0.f, 0.f, 0.f};

    for (int st = 0; st < N_STAGES; ++st) {
        const short* Ws = wbuf + (st & 1) * (STAGE_C * 1280);

        // issue W[st+1] DMA into the buffer last read at stage st-1
        if (st >= 1 && st < N_STAGES - 1) {
            const char* src =
                (const char*)(Wb + (size_t)(c0 + (st + 1) * STAGE_C) * 1280);
            char* dst = (char*)(wbuf + ((st + 1) & 1) * (STAGE_C * 1280));
            #pragma unroll
            for (int it = 0; it < 2; ++it) {
                int f = tid + BLOCK * it;
                if (f < 480) GLD16(src + f * 16, dst + f * 16);
            }
            asm volatile("" ::: "memory");
        }

        if (!FIRST) {
            // ---- sweep1: 30 independent (c,n) chains over 4 waves ----
            #pragma unroll
            for (int k = 0; k < 8; ++k) {
                const int idx = wv + 4 * k;
                if (idx < 30) {
                    const int c = idx / 10;
                    const int n = idx - c * 10;
                    v8s wa = {0, 0, 0, 0, 0, 0, 0, 0};
                    if (quad == 0)
                        wa = *(const v8s*)(Ws + c * 1280 + n * 128 + b * 8);
                    const v8s xb =
                        *(const v8s*)(xs + (st * STAGE_C + c) * 128 + b * 8);
                    v4f u = __builtin_amdgcn_mfma_f32_16x16x32_bf16(
                        wa, xb, (v4f){0.f, 0.f, 0.f, 0.f}, 0, 0, 0);
                    // v row from registers: chain k uses vreg[k%5] (literal k)
                    const v4f vv = (k % 5 == 0) ? vr0
                                 : (k % 5 == 1) ? vr1
                                 : (k % 5 == 2) ? vr2
                                 : (k % 5 == 3) ? vr3 : vr4;
                    float l = u[0] * vv[0] + u[1] * vv[1]
                            + u[2] * vv[2] + u[3] * vv[3];
                    l += __shfl_xor(l, 16);
                    l += __shfl_xor(l, 32);
                    const float e1 = __expf(l);   // |l| <~ 3: no max-sub needed
                    if (quad == 0) cfl[c * 163 + n * 16 + b] = e1;
                }
            }
            // publish cfl; W[st+1] DMA stays in flight (no vmcnt drain)
            asm volatile("s_waitcnt lgkmcnt(0)" ::: "memory");
            __builtin_amdgcn_s_barrier();
        }

        // ---- sweep2: K=32 packs 3 c's (quad=c, quad3 zero-padded) ----
        {
            const bool valid = (quad < STAGE_C);
            const int  cl    = valid ? quad : 0;
            const v8s xq =
                *(const v8s*)(xs + (st * STAGE_C + cl) * 128 + b * 8);
            float xf[8];
            #pragma unroll
            for (int j = 0; j < 8; ++j) xf[j] = bf2f(xq[j]);

            if (FIRST) {
                union { v8s s; uint32_t u[4]; } zu;
                zu.u[0] = cvtpk(0.1f * xf[0], 0.1f * xf[1]);
                zu.u[1] = cvtpk(0.1f * xf[2], 0.1f * xf[3]);
                zu.u[2] = cvtpk(0.1f * xf[4], 0.1f * xf[5]);
                zu.u[3] = cvtpk(0.1f * xf[6], 0.1f * xf[7]);
                #pragma unroll
                for (int jj = 0; jj < 3; ++jj) {
                    if (jj < ncnt) {
                        const int n = wv + 4 * jj;
                        v8s wa = {0, 0, 0, 0, 0, 0, 0, 0};
                        if (valid)
                            wa = *(const v8s*)(Ws + cl * 1280 + n * 128 + b * 8);
                        sacc[jj] = __builtin_amdgcn_mfma_f32_16x16x32_bf16(
                            wa, zu.s, sacc[jj], 0, 0, 0);
                    }
                }
            } else {
                float Z = 0.f;
                #pragma unroll
                for (int n = 0; n < N_N; ++n) Z += cfl[cl * 163 + n * 16 + b];
                const float rzv = __builtin_amdgcn_rcpf(Z);
                #pragma unroll
                for (int jj = 0; jj < 3; ++jj) {
                    if (jj < ncnt) {
                        const int n = wv + 4 * jj;
                        const float cv = cfl[cl * 163 + n * 16 + b] * rzv;
                        union { v8s s; uint32_t u[4]; } zu;
                        zu.u[0] = cvtpk(cv * xf[0], cv * xf[1]);
                        zu.u[1] = cvtpk(cv * xf[2], cv * xf[3]);
                        zu.u[2] = cvtpk(cv * xf[4], cv * xf[5]);
                        zu.u[3] = cvtpk(cv * xf[6], cv * xf[7]);
                        v8s wa = {0, 0, 0, 0, 0, 0, 0, 0};
                        if (valid)
                            wa = *(const v8s*)(Ws + cl * 1280 + n * 128 + b * 8);
                        sacc[jj] = __builtin_amdgcn_mfma_f32_16x16x32_bf16(
                            wa, zu.s, sacc[jj], 0, 0, 0);
                    }
                }
            }
        }

        // end of stage: W[st+1] had a full stage of compute to land
        asm volatile("s_waitcnt vmcnt(0) lgkmcnt(0)" ::: "memory");
        __builtin_amdgcn_s_barrier();
    }

    // ---- tail: prefetch next pass's W (same c-slice) into freed wbuf;
    //      drains for free inside the following gbar's vmcnt(0) ----
    if (PREFETCH) {
        #pragma unroll
        for (int s0 = 0; s0 < 2; ++s0) {
            const char* src =
                (const char*)(Wb + (size_t)(c0 + s0 * STAGE_C) * 1280);
            char* dst = (char*)(wbuf + s0 * (STAGE_C * 1280));
            #pragma unroll
            for (int it = 0; it < 2; ++it) {
                int f = tid + BLOCK * it;
                if (f < 480) GLD16(src + f * 16, dst + f * 16);
            }
            asm volatile("" ::: "memory");
        }
    }

    // ---- direct reg -> p_s sc1 stores ----
    #pragma unroll
    for (int jj = 0; jj < 3; ++jj) {
        if (jj < ncnt) {
            const int n = wv + 4 * jj;
            st16_sc1(&p_s[((size_t)chunk * B_N + gb0 + b) * 160 + n * 16 + quad * 4],
                     sacc[jj]);
        }
    }
}

// ---- reduce+squash, group-local: 160 g's over the group's 64 blocks ----
__device__ __forceinline__ void reduce_core(const float* __restrict__ p_s,
                                            float* __restrict__ vstG,
                                            float* __restrict__ out,
                                            int phase, int chunk, int btile)
{
    const int wv   = threadIdx.x >> 6;
    const int lane = threadIdx.x & 63;
    const int k    = wv * 64 + chunk;        // 0..191; valid < 160
    if (k >= 160) return;                    // wave-uniform (chunk is uniform)
    const int bb = k / 10, n = k - bb * 10;  // bb in [0,16), n in [0,10)
    const int g  = (btile * 16 + bb) * 10 + n;
    const int q = lane & 3;
    const int h = lane >> 2;

    // p_s written cross-block -> sc1 loads (bypass possibly-stale L2)
    const float* base = p_s + (size_t)g * D_N + q * 4;
    v4f a0, a1, a2, a3;
    asm volatile(
        "global_load_dwordx4 %0, %4, off sc1\n\t"
        "global_load_dwordx4 %1, %5, off sc1\n\t"
        "global_load_dwordx4 %2, %6, off sc1\n\t"
        "global_load_dwordx4 %3, %7, off sc1\n\t"
        "s_waitcnt vmcnt(0)"
        : "=&v"(a0), "=&v"(a1), "=&v"(a2), "=&v"(a3)
        : "v"(base + (size_t)(h)      * 40960),
          "v"(base + (size_t)(h + 16) * 40960),
          "v"(base + (size_t)(h + 32) * 40960),
          "v"(base + (size_t)(h + 48) * 40960)
        : "memory");
    v4f s = a0 + a1 + a2 + a3;

    #pragma unroll
    for (int off = 4; off < 64; off <<= 1) {
        s[0] += __shfl_xor(s[0], off);
        s[1] += __shfl_xor(s[1], off);
        s[2] += __shfl_xor(s[2], off);
        s[3] += __shfl_xor(s[3], off);
    }
    float sq = s[0] * s[0] + s[1] * s[1] + s[2] * s[2] + s[3] * s[3];
    sq += __shfl_xor(sq, 1);
    sq += __shfl_xor(sq, 2);

    const float scale = (sq / (1.f + sq)) / (sqrtf(sq) + 1e-8f);
    const v4f v = {scale * s[0], scale * s[1], scale * s[2], scale * s[3]};

    if (h == 0) {
        if (phase == 2) {
            *(float4*)(&out[(size_t)g * D_N + q * 4]) =
                make_float4(v[0], v[1], v[2], v[3]);   // plain: kernel-end flush
        } else {
            float* vp = vstG + (size_t)btile * 2624 + bb * 164 + n * 16 + q * 4;
            if (phase == 0) {
                st16_sc1(vp, v);
            } else {
                v4f o = ld16_sc1(vp);   // own phase-0 sc1 store, via LLC
                st16_sc1(vp, o + v);
            }
        }
    }
}

// ---- whole routing pipeline, ONE dispatch, per-group barriers only ----
__global__ __launch_bounds__(BLOCK, 4)
void fused_route(const float* __restrict__ x, const short* __restrict__ Wb,
                 float* __restrict__ vstG, float* __restrict__ p_s,
                 float* __restrict__ out, uint32_t* bar)
{
    __shared__ __align__(16) char pool[POOL_BYTES];
    short* wbuf = (short*)pool;
    short* xs   = (short*)(pool + 15360);
    float* cfl  = (float*)(pool + 19968);

    const int chunk = blockIdx.x;
    const int btile = blockIdx.y;     // == group id
    const int tid   = threadIdx.x;
    const int gb0   = btile * 16;
    const int c0    = chunk * C_PER;

    // ---- xs: convert x fp32 -> bf16 straight into LDS; persists all passes ----
    {
        const float4* x4 = (const float4*)x;
        #pragma unroll
        for (int it = 0; it < 3; ++it) {
            int f = tid + BLOCK * it;
            if (f < 576) {
                int b = f / 36, r = f - b * 36;  // r: 36 float4 per b (18c*8i)
                float4 v = x4[(size_t)(gb0 + b) * 2304 + c0 * 2 + r];
                int cp = r >> 1, i0 = (r & 1) * 4;
                *(uint2*)(xs + cp * 128 + b * 8 + i0) =
                    make_uint2(cvtpk(v.x, v.y), cvtpk(v.z, v.w));
            }
        }
        // drain x loads so the prologue's vmcnt(2) counts only W DMA
        asm volatile("s_waitcnt vmcnt(0)" ::: "memory");
    }

    // pass 0: c = 0.1 uniform; W staged in prologue; prefetch W at tail
    route_core<true, false, true>(wbuf, xs, cfl, Wb, vstG, p_s, chunk, btile);
    gbar(bar, btile, 1);
    reduce_core(p_s, vstG, out, 0, chunk, btile);
    gbar(bar, btile, 2);

    // pass 1: W prestaged (drained at gbar 1); prefetch again at tail
    route_core<false, true, true>(wbuf, xs, cfl, Wb, vstG, p_s, chunk, btile);
    gbar(bar, btile, 3);
    reduce_core(p_s, vstG, out, 1, chunk, btile);
    gbar(bar, btile, 4);

    // pass 2: W prestaged; no prefetch
    route_core<false, true, false>(wbuf, xs, cfl, Wb, vstG, p_s, chunk, btile);
    gbar(bar, btile, 5);
    reduce_core(p_s, vstG, out, 2, chunk, btile);
}

extern "C" void kernel_launch(void* const* d_in, const int* in_sizes, int n_in,
                              void* d_out, int out_size, void* d_ws, size_t ws_size,
                              hipStream_t stream)
{
    const float* x = (const float*)d_in[0];
    const float* W = (const float*)d_in[1];
    float* out  = (float*)d_out;

    float* vstG = (float*)d_ws;
    float* p_s  = vstG + VSTG_FL;
    short* Wb   = (short*)(p_s + PS_FL);
    uint32_t* bar = (uint32_t*)(Wb + WB_SH);

    conv_all<<<dim3(144), BLOCK, 0, stream>>>(W, Wb, bar);
    fused_route<<<dim3(C_CHUNKS, 16), BLOCK, 0, stream>>>(x, Wb, vstG, p_s, out, bar);
}